// Round 4
// baseline (662.078 us; speedup 1.0000x reference)
//
#include <hip/hip_runtime.h>

typedef unsigned short u16;
typedef __attribute__((ext_vector_type(8))) short short8;
typedef __attribute__((ext_vector_type(4))) float floatx4;

#define MFMA16(A, B, C) __builtin_amdgcn_mfma_f32_16x16x32_bf16((A), (B), (C), 0, 0, 0)

// ws layout (u16 element offsets)
#define OF_SPEC  64
#define OF_SMALL (OF_SPEC + 204800)
#define OF_W     (OF_SMALL + 2048)
#define OF_WP    (OF_W + 5 * 65536)

static __device__ __forceinline__ float bf2f(u16 u) {
  union { unsigned int i; float f; } z; z.i = ((unsigned int)u) << 16; return z.f;
}
static __device__ __forceinline__ u16 f2bf(float f) {
  union { float f; unsigned int i; } z; z.f = f;
  unsigned int x = z.i + 0x7fffu + ((z.i >> 16) & 1u);  // RNE
  return (u16)(x >> 16);
}
static __device__ __forceinline__ void ld8f(const u16* p, float* o) {
  union { short8 v; u16 u[8]; } t;
  t.v = *(const short8*)p;
#pragma unroll
  for (int j = 0; j < 8; ++j) o[j] = bf2f(t.u[j]);
}

__global__ void detect_kernel(const u16* __restrict__ spec_u16, int* __restrict__ flag) {
  const int lane = threadIdx.x;
  int bad = 0;
#pragma unroll
  for (int j = 0; j < 4; ++j) {
    u16 v = spec_u16[lane * 4 + j];
    int e = (v >> 7) & 0xFF;
    bad += (e >= 137);
  }
  unsigned long long m = __ballot(bad > 0);
  if (lane == 0) *flag = (__popcll(m) >= 4) ? 1 : 0;
}

#define CV(src, idx) (flag ? f2bf(((const float*)(src))[idx]) : ((const u16*)(src))[idx])

__global__ void prep_kernel(
    const int* __restrict__ flagp,
    const void* spec, const void* W1, const void* b1, const void* W2, const void* b2,
    const void* Wq, const void* bq, const void* Wk, const void* bk, const void* Wv,
    const void* bv, const void* Wo, const void* bo, const void* Wp, const void* bp,
    u16* __restrict__ ws) {
  const int flag = *flagp;
  int i = blockIdx.x * 256 + threadIdx.x;
  if (i < 204800) { ws[OF_SPEC + i] = CV(spec, i); return; }
  int j = i - 204800;
  if (j < 2048) {
    const void* srcs[8] = {W1, b1, b2, bq, bk, bv, bo, bp};
    ws[OF_SMALL + j] = CV(srcs[j >> 8], j & 255);
    return;
  }
  j -= 2048;
  if (j < 327680) {
    const void* srcs[5] = {W2, Wq, Wk, Wv, Wo};
    const int a = j >> 16, idx = j & 65535;
    const int k = idx >> 8, n = idx & 255;
    ws[OF_W + a * 65536 + (k >> 3) * 2048 + n * 8 + (k & 7)] = CV(srcs[a], idx);
    return;
  }
  j -= 327680;
  {
    const int k = j >> 8, n = j & 255;
    ws[OF_WP + (k >> 3) * 2048 + n * 8 + (k & 7)] = CV(Wp, j);
  }
}

// One block = 64 tokens = 8 windows = 4 window-pairs. 8 chunks of 1 head.
// Attention fully on MFMA: scores 16x16x32 per (wpair,head); softmax in
// C-layout via shfl; P->A-frag via in-place LDS alias; PV 2 MFMA.
__global__ __launch_bounds__(256, 3) void fused_kernel(
    const u16* __restrict__ csp, const u16* __restrict__ csm,
    const u16* __restrict__ sW2, const u16* __restrict__ sWq,
    const u16* __restrict__ sWk, const u16* __restrict__ sWv,
    const u16* __restrict__ sWo, const u16* __restrict__ sWp,
    const int* __restrict__ flagp,
    void* __restrict__ out)
{
  __shared__ u16 lds[22528];          // 45056 B -> 3 blocks/CU
  u16* eA = lds;                      // [0,16384): frag-major e A[m64][k256]; later patchA
  u16* QA = lds + 16384;              // [4 wp][4 dblk][16 m][8]  (Q; pA aliases per-wave)
  u16* KB = lds + 18432;              // same layout (K)
  u16* VB = lds + 20480;              // [4 wp][2 dh][2 kq][16 n][8]; obA' aliases per-wp

  const u16* cW1 = csm;
  const u16* cb1 = csm + 256;
  const u16* cb2 = csm + 512;
  const u16* cbq = csm + 768;
  const u16* cbk = csm + 1024;
  const u16* cbv = csm + 1280;
  const u16* cbo = csm + 1536;
  const u16* cbp = csm + 1792;

  const int flag = *flagp;
  const int tid = threadIdx.x;
  const int w = tid >> 6, lane = tid & 63;
  const int l15 = lane & 15, quad = lane >> 4;
  const int tile0 = blockIdx.x * 64;

  float sv[4];
#pragma unroll
  for (int mi = 0; mi < 4; ++mi) sv[mi] = bf2f(csp[tile0 + mi * 16 + l15]);

  // ---------------- phase 0: e tile -> eA fragment-major ----------------
  {
    const int nbase = w * 64;
    floatx4 acc[4][4];
#pragma unroll
    for (int mi = 0; mi < 4; ++mi)
#pragma unroll
      for (int ni = 0; ni < 4; ++ni) acc[mi][ni] = (floatx4){0.f, 0.f, 0.f, 0.f};
    for (int kc = 0; kc < 8; ++kc) {
      const int k0 = kc * 32 + quad * 8;
      float w1f[8], b1f[8];
      ld8f(cW1 + k0, w1f);
      ld8f(cb1 + k0, b1f);
      short8 afr[4];
#pragma unroll
      for (int mi = 0; mi < 4; ++mi) {
        union { short8 s; u16 u[8]; } av;
#pragma unroll
        for (int j = 0; j < 8; ++j) {
          float x = fmaf(sv[mi], w1f[j], b1f[j]);
          av.u[j] = f2bf(x > 0.f ? x : 0.f);
        }
        afr[mi] = av.s;
      }
#pragma unroll
      for (int ni = 0; ni < 4; ++ni) {
        short8 bfr = *(const short8*)(sW2 + ((kc * 4 + quad) * 256 + nbase + ni * 16 + l15) * 8);
#pragma unroll
        for (int mi = 0; mi < 4; ++mi) acc[mi][ni] = MFMA16(afr[mi], bfr, acc[mi][ni]);
      }
    }
#pragma unroll
    for (int ni = 0; ni < 4; ++ni) {
      const int n = nbase + ni * 16 + l15;
      const float bb = bf2f(cb2[n]);
      const int blk = (n >> 3) * 512 + (n & 7);
#pragma unroll
      for (int mi = 0; mi < 4; ++mi)
#pragma unroll
        for (int r = 0; r < 4; ++r)
          eA[blk + (mi * 16 + quad * 4 + r) * 8] = f2bf(acc[mi][ni][r] + bb);
    }
  }
  __syncthreads();

  floatx4 ooacc[4][4];
#pragma unroll
  for (int mi = 0; mi < 4; ++mi)
#pragma unroll
    for (int ni = 0; ni < 4; ++ni) ooacc[mi][ni] = (floatx4){0.f, 0.f, 0.f, 0.f};

  // ---------------- 8 chunks of 1 head (32 cols) ------------------------
  for (int h = 0; h < 8; ++h) {
    // QKV GEMM: wave covers mi-pair (w>>1)*2..+2, col-half (w&1)*16
    {
      const int mi0 = (w >> 1) * 2;
      const int colq = h * 32 + (w & 1) * 16 + l15;
      floatx4 facc[3][2];
#pragma unroll
      for (int x = 0; x < 3; ++x)
#pragma unroll
        for (int mm = 0; mm < 2; ++mm) facc[x][mm] = (floatx4){0.f, 0.f, 0.f, 0.f};
      for (int kc = 0; kc < 8; ++kc) {
        short8 afr[2];
#pragma unroll
        for (int mm = 0; mm < 2; ++mm)
          afr[mm] = *(const short8*)(eA + (kc * 4 + quad) * 512 + ((mi0 + mm) * 16 + l15) * 8);
        const int wo = ((kc * 4 + quad) * 256 + colq) * 8;
        short8 bq8 = *(const short8*)(sWq + wo);
        short8 bk8 = *(const short8*)(sWk + wo);
        short8 bv8 = *(const short8*)(sWv + wo);
#pragma unroll
        for (int mm = 0; mm < 2; ++mm) {
          facc[0][mm] = MFMA16(afr[mm], bq8, facc[0][mm]);
          facc[1][mm] = MFMA16(afr[mm], bk8, facc[1][mm]);
          facc[2][mm] = MFMA16(afr[mm], bv8, facc[2][mm]);
        }
      }
      const float bqv = bf2f(cbq[colq]), bkv = bf2f(cbk[colq]), bvv = bf2f(cbv[colq]);
      const int dblk = (w & 1) * 2 + (l15 >> 3), d7 = l15 & 7;
#pragma unroll
      for (int mm = 0; mm < 2; ++mm) {
        const int wp = (w >> 1) * 2 + mm;
#pragma unroll
        for (int r = 0; r < 4; ++r) {
          const int m15 = quad * 4 + r;
          QA[wp * 512 + dblk * 128 + m15 * 8 + d7] = f2bf(facc[0][mm][r] + bqv);
          KB[wp * 512 + dblk * 128 + m15 * 8 + d7] = f2bf(facc[1][mm][r] + bkv);
          VB[wp * 512 + (w & 1) * 256 + (m15 >> 3) * 128 + l15 * 8 + (m15 & 7)] =
              f2bf(facc[2][mm][r] + bvv);
        }
      }
    }
    __syncthreads();   // B1: qkv staged

    // attention for wpair w: scores MFMA -> softmax -> P in-place -> PV
    {
      u16* qw = QA + w * 512;
      short8 aq = *(const short8*)(qw + quad * 128 + l15 * 8);
      short8 bk = *(const short8*)(KB + w * 512 + quad * 128 + l15 * 8);
      floatx4 sacc = MFMA16(aq, bk, ((floatx4){0.f, 0.f, 0.f, 0.f}));
      const int valid = ((l15 >> 3) == (quad >> 1));
      u16 pb[4];
#pragma unroll
      for (int r = 0; r < 4; ++r) {
        float s = valid ? sacc[r] * 0.17677669529663687f : -1e30f;
        float mx = s;
        mx = fmaxf(mx, __shfl_xor(mx, 1));
        mx = fmaxf(mx, __shfl_xor(mx, 2));
        mx = fmaxf(mx, __shfl_xor(mx, 4));
        mx = fmaxf(mx, __shfl_xor(mx, 8));
        float p = __expf(s - mx);
        float su = p;
        su += __shfl_xor(su, 1);
        su += __shfl_xor(su, 2);
        su += __shfl_xor(su, 4);
        su += __shfl_xor(su, 8);
        pb[r] = f2bf(p * (1.0f / su));
      }
      // P -> A-frag, aliasing qw (this wave already consumed Q). Zeros in
      // quads 2,3 (k'=16..31); DS same-wave ordering keeps read-before-write.
      *(unsigned long long*)(qw + 256 + lane * 4) = 0ULL;
#pragma unroll
      for (int r = 0; r < 4; ++r)
        qw[(l15 >> 3) * 128 + (quad * 4 + r) * 8 + (l15 & 7)] = pb[r];

      short8 ap = *(const short8*)(qw + quad * 128 + l15 * 8);
      floatx4 oacc[2];
#pragma unroll
      for (int dh = 0; dh < 2; ++dh) {
        short8 bv = *(const short8*)(VB + w * 512 + dh * 256 + (quad & 1) * 128 + l15 * 8);
        oacc[dh] = MFMA16(ap, bv, ((floatx4){0.f, 0.f, 0.f, 0.f}));
      }
      // O -> obA' (aliases VB[w], own region): frag-major for Wo A-reads
#pragma unroll
      for (int dh = 0; dh < 2; ++dh)
#pragma unroll
        for (int r = 0; r < 4; ++r) {
          const int m15 = quad * 4 + r;
          VB[w * 512 + (dh * 2 + (l15 >> 3)) * 128 + m15 * 8 + (l15 & 7)] = f2bf(oacc[dh][r]);
        }
    }
    __syncthreads();   // B2: O staged

    // Wo partial accumulate over this head's 32-col K-slice
    {
      short8 afr[4];
#pragma unroll
      for (int mi = 0; mi < 4; ++mi)
        afr[mi] = *(const short8*)(VB + mi * 512 + quad * 128 + l15 * 8);
#pragma unroll
      for (int ni = 0; ni < 4; ++ni) {
        const int n = w * 64 + ni * 16 + l15;
        short8 bfr = *(const short8*)(sWo + ((h * 4 + quad) * 256 + n) * 8);
#pragma unroll
        for (int mi = 0; mi < 4; ++mi) ooacc[mi][ni] = MFMA16(afr[mi], bfr, ooacc[mi][ni]);
      }
    }
    __syncthreads();   // B3: obA'/VB consumed, safe for next chunk's staging
  }

  // oo (+bo) -> patchA (eA region): k = p*256 + n -> ((p*32 + (n>>3))*64 + w*8 + (n&7))
#pragma unroll
  for (int ni = 0; ni < 4; ++ni) {
    const int n = w * 64 + ni * 16 + l15;
    const float bb = bf2f(cbo[n]);
    const int nb8 = (n >> 3) * 64 + (n & 7);
#pragma unroll
    for (int mi = 0; mi < 4; ++mi)
#pragma unroll
      for (int r = 0; r < 4; ++r) {
        const int tr = mi * 16 + quad * 4 + r;
        eA[(tr >> 3) * 8 + ((tr & 7) * 32) * 64 + nb8] = f2bf(ooacc[mi][ni][r] + bb);
      }
  }
  __syncthreads();

  // ---------------- patch projection: [8 x 2048] @ Wp + bp ----------------
  {
    const int w8 = (l15 & 7) * 8;
    floatx4 pacc[4];
#pragma unroll
    for (int ni = 0; ni < 4; ++ni) pacc[ni] = (floatx4){0.f, 0.f, 0.f, 0.f};
#pragma unroll 4
    for (int kc = 0; kc < 64; ++kc) {
      short8 afr = *(const short8*)(eA + (kc * 4 + quad) * 64 + w8);
#pragma unroll
      for (int ni = 0; ni < 4; ++ni) {
        const int n = w * 64 + ni * 16 + l15;
        short8 bfr = *(const short8*)(sWp + ((kc * 4 + quad) * 256 + n) * 8);
        pacc[ni] = MFMA16(afr, bfr, pacc[ni]);
      }
    }
    if (quad < 2) {
      if (flag) {
        float* po = (float*)out;
#pragma unroll
        for (int ni = 0; ni < 4; ++ni) {
          const int n = w * 64 + ni * 16 + l15;
          const float bb = bf2f(cbp[n]);
#pragma unroll
          for (int r = 0; r < 4; ++r)
            po[(blockIdx.x * 8 + quad * 4 + r) * 256 + n] = pacc[ni][r] + bb;
        }
      } else {
        u16* po = (u16*)out;
#pragma unroll
        for (int ni = 0; ni < 4; ++ni) {
          const int n = w * 64 + ni * 16 + l15;
          const float bb = bf2f(cbp[n]);
#pragma unroll
          for (int r = 0; r < 4; ++r)
            po[(blockIdx.x * 8 + quad * 4 + r) * 256 + n] = f2bf(pacc[ni][r] + bb);
        }
      }
    }
  }
}

extern "C" void kernel_launch(void* const* d_in, const int* in_sizes, int n_in,
                              void* d_out, int out_size, void* d_ws, size_t ws_size,
                              hipStream_t stream) {
  (void)in_sizes; (void)n_in; (void)out_size; (void)ws_size;
  int* flag = (int*)d_ws;
  u16* ws = (u16*)d_ws;

  detect_kernel<<<1, 64, 0, stream>>>((const u16*)d_in[0], flag);
  prep_kernel<<<4136, 256, 0, stream>>>(flag,
      d_in[0], d_in[1], d_in[2], d_in[3], d_in[4], d_in[5], d_in[6], d_in[7],
      d_in[8], d_in[9], d_in[10], d_in[11], d_in[12], d_in[13], d_in[14], ws);
  fused_kernel<<<3200, 256, 0, stream>>>(
      ws + OF_SPEC, ws + OF_SMALL,
      ws + OF_W, ws + OF_W + 65536, ws + OF_W + 2 * 65536,
      ws + OF_W + 3 * 65536, ws + OF_W + 4 * 65536, ws + OF_WP,
      flag, d_out);
}

// Round 5
// 493.542 us; speedup vs baseline: 1.3415x; 1.3415x over previous
//
#include <hip/hip_runtime.h>

typedef unsigned short u16;
typedef __attribute__((ext_vector_type(8))) short short8;
typedef __attribute__((ext_vector_type(4))) float floatx4;

#define MFMA16(A, B, C) __builtin_amdgcn_mfma_f32_16x16x32_bf16((A), (B), (C), 0, 0, 0)

// ws layout (u16 element offsets)
#define OF_SPEC  64
#define OF_SMALL (OF_SPEC + 204800)
#define OF_W     (OF_SMALL + 2048)
#define OF_WP    (OF_W + 5 * 65536)

static __device__ __forceinline__ float bf2f(u16 u) {
  union { unsigned int i; float f; } z; z.i = ((unsigned int)u) << 16; return z.f;
}
static __device__ __forceinline__ u16 f2bf(float f) {
  union { float f; unsigned int i; } z; z.f = f;
  unsigned int x = z.i + 0x7fffu + ((z.i >> 16) & 1u);  // RNE
  return (u16)(x >> 16);
}
static __device__ __forceinline__ void ld8f(const u16* p, float* o) {
  union { short8 v; u16 u[8]; } t;
  t.v = *(const short8*)p;
#pragma unroll
  for (int j = 0; j < 8; ++j) o[j] = bf2f(t.u[j]);
}

__global__ void detect_kernel(const u16* __restrict__ spec_u16, int* __restrict__ flag) {
  const int lane = threadIdx.x;
  int bad = 0;
#pragma unroll
  for (int j = 0; j < 4; ++j) {
    u16 v = spec_u16[lane * 4 + j];
    int e = (v >> 7) & 0xFF;
    bad += (e >= 137);
  }
  unsigned long long m = __ballot(bad > 0);
  if (lane == 0) *flag = (__popcll(m) >= 4) ? 1 : 0;
}

#define CV(src, idx) (flag ? f2bf(((const float*)(src))[idx]) : ((const u16*)(src))[idx])

__global__ void prep_kernel(
    const int* __restrict__ flagp,
    const void* spec, const void* W1, const void* b1, const void* W2, const void* b2,
    const void* Wq, const void* bq, const void* Wk, const void* bk, const void* Wv,
    const void* bv, const void* Wo, const void* bo, const void* Wp, const void* bp,
    u16* __restrict__ ws) {
  const int flag = *flagp;
  int i = blockIdx.x * 256 + threadIdx.x;
  if (i < 204800) { ws[OF_SPEC + i] = CV(spec, i); return; }
  int j = i - 204800;
  if (j < 2048) {
    const void* srcs[8] = {W1, b1, b2, bq, bk, bv, bo, bp};
    ws[OF_SMALL + j] = CV(srcs[j >> 8], j & 255);
    return;
  }
  j -= 2048;
  if (j < 327680) {
    const void* srcs[5] = {W2, Wq, Wk, Wv, Wo};
    const int a = j >> 16, idx = j & 65535;
    const int k = idx >> 8, n = idx & 255;
    ws[OF_W + a * 65536 + (k >> 3) * 2048 + n * 8 + (k & 7)] = CV(srcs[a], idx);
    return;
  }
  j -= 327680;
  {
    const int k = j >> 8, n = j & 255;
    ws[OF_WP + (k >> 3) * 2048 + n * 8 + (k & 7)] = CV(Wp, j);
  }
}

// One block = 64 tokens = 8 windows = 4 window-pairs. 8 chunks of 1 head.
// MFMA attention (proven r4). Wo accumulation is own-wave (wave w holds its
// wpair's 16 rows x all 256 cols) so only 2 barriers per chunk survive.
__global__ __launch_bounds__(256, 2) void fused_kernel(
    const u16* __restrict__ csp, const u16* __restrict__ csm,
    const u16* __restrict__ sW2, const u16* __restrict__ sWq,
    const u16* __restrict__ sWk, const u16* __restrict__ sWv,
    const u16* __restrict__ sWo, const u16* __restrict__ sWp,
    const int* __restrict__ flagp,
    void* __restrict__ out)
{
  __shared__ u16 lds[22528];          // 45056 B
  u16* eA = lds;                      // [0,16384): frag-major e A[m64][k256]; later patchA
  u16* QA = lds + 16384;              // [4 wp][4 dblk][16 m][8]  (Q; P aliases per-wave)
  u16* KB = lds + 18432;              // same layout (K)
  u16* VB = lds + 20480;              // [4 wp][2 dh][2 kq][16 n][8]; O aliases per-wave

  const u16* cW1 = csm;
  const u16* cb1 = csm + 256;
  const u16* cb2 = csm + 512;
  const u16* cbq = csm + 768;
  const u16* cbk = csm + 1024;
  const u16* cbv = csm + 1280;
  const u16* cbo = csm + 1536;
  const u16* cbp = csm + 1792;

  const int flag = *flagp;
  const int tid = threadIdx.x;
  const int w = tid >> 6, lane = tid & 63;
  const int l15 = lane & 15, quad = lane >> 4;
  const int tile0 = blockIdx.x * 64;

  float sv[4];
#pragma unroll
  for (int mi = 0; mi < 4; ++mi) sv[mi] = bf2f(csp[tile0 + mi * 16 + l15]);

  // ---------------- phase 0: e tile -> eA fragment-major ----------------
  {
    const int nbase = w * 64;
    floatx4 acc[4][4];
#pragma unroll
    for (int mi = 0; mi < 4; ++mi)
#pragma unroll
      for (int ni = 0; ni < 4; ++ni) acc[mi][ni] = (floatx4){0.f, 0.f, 0.f, 0.f};
    for (int kc = 0; kc < 8; ++kc) {
      const int k0 = kc * 32 + quad * 8;
      float w1f[8], b1f[8];
      ld8f(cW1 + k0, w1f);
      ld8f(cb1 + k0, b1f);
      short8 afr[4];
#pragma unroll
      for (int mi = 0; mi < 4; ++mi) {
        union { short8 s; u16 u[8]; } av;
#pragma unroll
        for (int j = 0; j < 8; ++j) {
          float x = fmaf(sv[mi], w1f[j], b1f[j]);
          av.u[j] = f2bf(x > 0.f ? x : 0.f);
        }
        afr[mi] = av.s;
      }
#pragma unroll
      for (int ni = 0; ni < 4; ++ni) {
        short8 bfr = *(const short8*)(sW2 + ((kc * 4 + quad) * 256 + nbase + ni * 16 + l15) * 8);
#pragma unroll
        for (int mi = 0; mi < 4; ++mi) acc[mi][ni] = MFMA16(afr[mi], bfr, acc[mi][ni]);
      }
    }
#pragma unroll
    for (int ni = 0; ni < 4; ++ni) {
      const int n = nbase + ni * 16 + l15;
      const float bb = bf2f(cb2[n]);
      const int blk = (n >> 3) * 512 + (n & 7);
#pragma unroll
      for (int mi = 0; mi < 4; ++mi)
#pragma unroll
        for (int r = 0; r < 4; ++r)
          eA[blk + (mi * 16 + quad * 4 + r) * 8] = f2bf(acc[mi][ni][r] + bb);
    }
  }
  __syncthreads();

  // Wo accumulator: own wpair's rows (w*16 + quad*4 + r) x cols (ni*16 + l15)
  floatx4 ooacc[16];
#pragma unroll
  for (int ni = 0; ni < 16; ++ni) ooacc[ni] = (floatx4){0.f, 0.f, 0.f, 0.f};

  // ---------------- 8 chunks of 1 head (32 cols) ------------------------
  for (int h = 0; h < 8; ++h) {
    // QKV GEMM: wave covers mi-pair (w>>1)*2..+2, col-half (w&1)*16
    {
      const int mi0 = (w >> 1) * 2;
      const int colq = h * 32 + (w & 1) * 16 + l15;
      floatx4 facc[3][2];
#pragma unroll
      for (int x = 0; x < 3; ++x)
#pragma unroll
        for (int mm = 0; mm < 2; ++mm) facc[x][mm] = (floatx4){0.f, 0.f, 0.f, 0.f};
      for (int kc = 0; kc < 8; ++kc) {
        short8 afr[2];
#pragma unroll
        for (int mm = 0; mm < 2; ++mm)
          afr[mm] = *(const short8*)(eA + (kc * 4 + quad) * 512 + ((mi0 + mm) * 16 + l15) * 8);
        const int wo = ((kc * 4 + quad) * 256 + colq) * 8;
        short8 bq8 = *(const short8*)(sWq + wo);
        short8 bk8 = *(const short8*)(sWk + wo);
        short8 bv8 = *(const short8*)(sWv + wo);
#pragma unroll
        for (int mm = 0; mm < 2; ++mm) {
          facc[0][mm] = MFMA16(afr[mm], bq8, facc[0][mm]);
          facc[1][mm] = MFMA16(afr[mm], bk8, facc[1][mm]);
          facc[2][mm] = MFMA16(afr[mm], bv8, facc[2][mm]);
        }
      }
      const float bqv = bf2f(cbq[colq]), bkv = bf2f(cbk[colq]), bvv = bf2f(cbv[colq]);
      const int dblk = (w & 1) * 2 + (l15 >> 3), d7 = l15 & 7;
#pragma unroll
      for (int mm = 0; mm < 2; ++mm) {
        const int wp = (w >> 1) * 2 + mm;
#pragma unroll
        for (int r = 0; r < 4; ++r) {
          const int m15 = quad * 4 + r;
          QA[wp * 512 + dblk * 128 + m15 * 8 + d7] = f2bf(facc[0][mm][r] + bqv);
          KB[wp * 512 + dblk * 128 + m15 * 8 + d7] = f2bf(facc[1][mm][r] + bkv);
          VB[wp * 512 + (w & 1) * 256 + (m15 >> 3) * 128 + l15 * 8 + (m15 & 7)] =
              f2bf(facc[2][mm][r] + bvv);
        }
      }
    }
    __syncthreads();   // B1: qkv staged (cross-wave)

    // attention + Wo for wpair w — entirely own-wave from here to chunk end
    {
      u16* qw = QA + w * 512;
      short8 aq = *(const short8*)(qw + quad * 128 + l15 * 8);
      short8 bk = *(const short8*)(KB + w * 512 + quad * 128 + l15 * 8);
      floatx4 sacc = MFMA16(aq, bk, ((floatx4){0.f, 0.f, 0.f, 0.f}));
      const int valid = ((l15 >> 3) == (quad >> 1));
      u16 pb[4];
#pragma unroll
      for (int r = 0; r < 4; ++r) {
        float s = valid ? sacc[r] * 0.17677669529663687f : -1e30f;
        float mx = s;
        mx = fmaxf(mx, __shfl_xor(mx, 1));
        mx = fmaxf(mx, __shfl_xor(mx, 2));
        mx = fmaxf(mx, __shfl_xor(mx, 4));
        mx = fmaxf(mx, __shfl_xor(mx, 8));
        float p = __expf(s - mx);
        float su = p;
        su += __shfl_xor(su, 1);
        su += __shfl_xor(su, 2);
        su += __shfl_xor(su, 4);
        su += __shfl_xor(su, 8);
        pb[r] = f2bf(p * (1.0f / su));
      }
      // P -> A-frag in-place over Q (own wave; DS ops are program-ordered)
      *(unsigned long long*)(qw + 256 + lane * 4) = 0ULL;
#pragma unroll
      for (int r = 0; r < 4; ++r)
        qw[(l15 >> 3) * 128 + (quad * 4 + r) * 8 + (l15 & 7)] = pb[r];

      short8 ap = *(const short8*)(qw + quad * 128 + l15 * 8);
      floatx4 oacc[2];
#pragma unroll
      for (int dh = 0; dh < 2; ++dh) {
        short8 bv = *(const short8*)(VB + w * 512 + dh * 256 + (quad & 1) * 128 + l15 * 8);
        oacc[dh] = MFMA16(ap, bv, ((floatx4){0.f, 0.f, 0.f, 0.f}));
      }
      // O -> own VB region, frag-major for the Wo A-read
#pragma unroll
      for (int dh = 0; dh < 2; ++dh)
#pragma unroll
        for (int r = 0; r < 4; ++r) {
          const int m15 = quad * 4 + r;
          VB[w * 512 + (dh * 2 + (l15 >> 3)) * 128 + m15 * 8 + (l15 & 7)] = f2bf(oacc[dh][r]);
        }

      // Wo partial accumulate: A = own O (M=16 rows of wpair w), N = 256
      short8 afr = *(const short8*)(VB + w * 512 + quad * 128 + l15 * 8);
#pragma unroll
      for (int ni = 0; ni < 16; ++ni) {
        const int n = ni * 16 + l15;
        short8 bfr = *(const short8*)(sWo + ((h * 4 + quad) * 256 + n) * 8);
        ooacc[ni] = MFMA16(afr, bfr, ooacc[ni]);
      }
    }
    __syncthreads();   // B2: QA/KB/VB consumed, safe for next chunk's staging
  }

  // oo (+bo) -> patchA (eA region). Wave w owns token rows w*16 + quad*4 + r.
  // k = p*256 + n -> addr (p*32 + (n>>3))*64 + win*8 + (n&7)
#pragma unroll
  for (int ni = 0; ni < 16; ++ni) {
    const int n = ni * 16 + l15;
    const float bb = bf2f(cbo[n]);
    const int nb8 = (n >> 3) * 64 + (n & 7);
#pragma unroll
    for (int r = 0; r < 4; ++r) {
      const int tr = w * 16 + quad * 4 + r;
      eA[((tr & 7) * 32) * 64 + (tr >> 3) * 8 + nb8] = f2bf(ooacc[ni][r] + bb);
    }
  }
  __syncthreads();

  // ---------------- patch projection: [8 x 2048] @ Wp + bp ----------------
  {
    const int w8 = (l15 & 7) * 8;
    floatx4 pacc[4];
#pragma unroll
    for (int ni = 0; ni < 4; ++ni) pacc[ni] = (floatx4){0.f, 0.f, 0.f, 0.f};
#pragma unroll 4
    for (int kc = 0; kc < 64; ++kc) {
      short8 afr = *(const short8*)(eA + (kc * 4 + quad) * 64 + w8);
#pragma unroll
      for (int ni = 0; ni < 4; ++ni) {
        const int n = w * 64 + ni * 16 + l15;
        short8 bfr = *(const short8*)(sWp + ((kc * 4 + quad) * 256 + n) * 8);
        pacc[ni] = MFMA16(afr, bfr, pacc[ni]);
      }
    }
    if (quad < 2) {
      if (flag) {
        float* po = (float*)out;
#pragma unroll
        for (int ni = 0; ni < 4; ++ni) {
          const int n = w * 64 + ni * 16 + l15;
          const float bb = bf2f(cbp[n]);
#pragma unroll
          for (int r = 0; r < 4; ++r)
            po[(blockIdx.x * 8 + quad * 4 + r) * 256 + n] = pacc[ni][r] + bb;
        }
      } else {
        u16* po = (u16*)out;
#pragma unroll
        for (int ni = 0; ni < 4; ++ni) {
          const int n = w * 64 + ni * 16 + l15;
          const float bb = bf2f(cbp[n]);
#pragma unroll
          for (int r = 0; r < 4; ++r)
            po[(blockIdx.x * 8 + quad * 4 + r) * 256 + n] = f2bf(pacc[ni][r] + bb);
        }
      }
    }
  }
}

extern "C" void kernel_launch(void* const* d_in, const int* in_sizes, int n_in,
                              void* d_out, int out_size, void* d_ws, size_t ws_size,
                              hipStream_t stream) {
  (void)in_sizes; (void)n_in; (void)out_size; (void)ws_size;
  int* flag = (int*)d_ws;
  u16* ws = (u16*)d_ws;

  detect_kernel<<<1, 64, 0, stream>>>((const u16*)d_in[0], flag);
  prep_kernel<<<4136, 256, 0, stream>>>(flag,
      d_in[0], d_in[1], d_in[2], d_in[3], d_in[4], d_in[5], d_in[6], d_in[7],
      d_in[8], d_in[9], d_in[10], d_in[11], d_in[12], d_in[13], d_in[14], ws);
  fused_kernel<<<3200, 256, 0, stream>>>(
      ws + OF_SPEC, ws + OF_SMALL,
      ws + OF_W, ws + OF_W + 65536, ws + OF_W + 2 * 65536,
      ws + OF_W + 3 * 65536, ws + OF_W + 4 * 65536, ws + OF_WP,
      flag, d_out);
}